// Round 4
// 459.516 us; speedup vs baseline: 1.0280x; 1.0280x over previous
//
#include <hip/hip_runtime.h>
#include <cstdint>
#include <cstddef>

// ---------------------------------------------------------------------------
// FFTFrequencyFilter: FFT highpass (== circular conv with per-channel 11x11
// kernel) -> 1x1 conv (GEMM, bf16 MFMA) -> BN -> ReLU -> gated residual.
// B=128, C=2048, H=W=11 (HW=121), N = B*HW = 15488.
// R8: R7 with global_load_lds offset arg retired (always 0); all K-advance
//     offsets folded into the GLOBAL POINTER (R4's proven pattern). The
//     builtin's offset-field semantics (global vs LDS dest) were the only
//     unverified element common to the R5-R7 failures.
//     Schedule/swizzle identical to R7 (vmcnt(0) drains at ph4/ph8).
//     prep/filter identical to R4.
// ---------------------------------------------------------------------------

#define C_DIM 2048
#define HW 121
#define NB 128
#define NTOT (NB * HW)  // 15488

__device__ __forceinline__ unsigned short f2bf(float f) {
  union { float f; unsigned int u; } v;
  v.f = f;
  unsigned int r = (v.u + 0x7FFFu + ((v.u >> 16) & 1u)) >> 16;
  return (unsigned short)r;
}

typedef __bf16 bfrag __attribute__((ext_vector_type(8)));
typedef float f32x4 __attribute__((ext_vector_type(4)));

__device__ __forceinline__ void gload16(const unsigned short* g, char* l) {
  __builtin_amdgcn_global_load_lds(
      (const __attribute__((address_space(1))) unsigned int*)(uintptr_t)g,
      (__attribute__((address_space(3))) unsigned int*)(uintptr_t)l, 16, 0, 0);
}

// ---------------------------------------------------------------------------
// Pass 1: per-channel spatial kernel k_c[11][11] (row-padded to 16 floats),
// epilogue constants alpha/beta2, AND W fp32->bf16 (row c per block).
// (unchanged from R4)
// ---------------------------------------------------------------------------
__global__ __launch_bounds__(256) void prep_kernel(
    const float* __restrict__ ft, const float* __restrict__ convb,
    const float* __restrict__ gamma, const float* __restrict__ beta,
    const float* __restrict__ mean, const float* __restrict__ var,
    const float* __restrict__ W, unsigned short* __restrict__ Wb,
    float* __restrict__ kws, float* __restrict__ alpha,
    float* __restrict__ beta2) {
  __shared__ float msk[121];
  __shared__ float ctab[11];
  const int c = blockIdx.x;
  const int t = threadIdx.x;

  {
    int base = c * C_DIM + t * 8;
    float4 a = *(const float4*)(W + base);
    float4 b = *(const float4*)(W + base + 4);
    union { unsigned short s[8]; uint4 v; } u;
    u.s[0] = f2bf(a.x); u.s[1] = f2bf(a.y); u.s[2] = f2bf(a.z); u.s[3] = f2bf(a.w);
    u.s[4] = f2bf(b.x); u.s[5] = f2bf(b.y); u.s[6] = f2bf(b.z); u.s[7] = f2bf(b.w);
    *(uint4*)(Wb + base) = u.v;
  }

  float cutoff = ft[c];
  cutoff = fminf(fmaxf(cutoff, 0.05f), 0.5f);
  if (t < 121) {
    int h = t / 11, w = t - (t / 11) * 11;
    float dy = (float)(h - 5), dx = (float)(w - 5);
    float dn = sqrtf(dy * dy + dx * dx) / (sqrtf(50.0f) + 1e-6f);
    msk[t] = 1.0f / (1.0f + expf(-10.0f * (dn - cutoff)));
  }
  if (t < 11) ctab[t] = cosf(6.283185307179586f * (float)t / 11.0f);
  if (t == 128) {
    float inv = gamma[c] * rsqrtf(var[c] + 1e-5f);
    alpha[c] = inv;
    beta2[c] = (convb[c] - mean[c]) * inv + beta[c];
  }
  __syncthreads();
  if (t < 176) {  // 11 rows x 16 padded cols
    int h = t >> 4, w = t & 15;
    float val = 0.0f;
    if (w < 11) {
      float acc = 0.0f;
      int ru = 0;
      int us = 5;
      for (int u = 0; u < 11; u++) {
        int rv = ru;
        int vs = 5;
        for (int v = 0; v < 11; v++) {
          acc += msk[us * 11 + vs] * ctab[rv];
          rv += w; if (rv >= 11) rv -= 11;
          vs++; if (vs >= 11) vs -= 11;
        }
        ru += h; if (ru >= 11) ru -= 11;
        us++; if (us >= 11) us -= 11;
      }
      val = acc * (1.0f / 121.0f);
    }
    kws[(size_t)c * 176 + t] = val;
  }
}

// ---------------------------------------------------------------------------
// Pass 2: circular conv filter using k's h-symmetry. (unchanged from R4)
// ---------------------------------------------------------------------------
#define XROW 12
#define XPL 132
#define FC 32
__global__ __launch_bounds__(384) void filter_kernel(
    const float* __restrict__ x, const float* __restrict__ kws,
    unsigned short* __restrict__ xf) {
  __shared__ __align__(16) float lx[FC * XPL];          // 16896 B
  __shared__ __align__(16) unsigned short lo[HW * FC];  // 7744 B
  const int b = blockIdx.x;
  const int c0 = blockIdx.y * FC;
  const int tid = threadIdx.x;

  const float* xsrc = x + ((size_t)b * C_DIM + c0) * HW;
#pragma unroll
  for (int i = 0; i < 3; i++) {
    int v = tid + i * 384;
    if (v < 968) {
      float4 xv = *(const float4*)(xsrc + v * 4);
      int g = v * 4;
#pragma unroll
      for (int e = 0; e < 4; e++) {
        int ge = g + e;
        int pl = ge / 121;
        int r = ge - pl * 121;
        int rh = r / 11;
        int rw = r - rh * 11;
        lx[pl * XPL + rh * XROW + rw] = (&xv.x)[e];
      }
    }
  }
  __syncthreads();

  if (tid < 352) {
    const int pl = tid / 11;
    const int ph = tid - pl * 11;
    const float* xp = &lx[pl * XPL];
    const float* kp = kws + (size_t)(c0 + pl) * 176;

    float accv[11];
#pragma unroll
    for (int i = 0; i < 11; i++) accv[i] = 0.f;

#pragma unroll
    for (int d = 0; d <= 5; d++) {
      int q0 = ph - d; if (q0 < 0) q0 += 11;
      f32x4 r0 = *(const f32x4*)(xp + q0 * XROW);
      f32x4 r1 = *(const f32x4*)(xp + q0 * XROW + 4);
      f32x4 r2 = *(const f32x4*)(xp + q0 * XROW + 8);
      if (d > 0) {
        int q1 = ph + d; if (q1 >= 11) q1 -= 11;
        r0 += *(const f32x4*)(xp + q1 * XROW);
        r1 += *(const f32x4*)(xp + q1 * XROW + 4);
        r2 += *(const f32x4*)(xp + q1 * XROW + 8);
      }
      const float R[11] = {r0[0], r0[1], r0[2], r0[3], r1[0], r1[1],
                           r1[2], r1[3], r2[0], r2[1], r2[2]};
      f32x4 k0 = *(const f32x4*)(kp + d * 16);
      f32x4 k1 = *(const f32x4*)(kp + d * 16 + 4);
      f32x4 k2 = *(const f32x4*)(kp + d * 16 + 8);
      const float K[11] = {k0[0], k0[1], k0[2], k0[3], k1[0], k1[1],
                           k1[2], k1[3], k2[0], k2[1], k2[2]};
#pragma unroll
      for (int qw = 0; qw < 11; qw++) {
#pragma unroll
        for (int pw = 0; pw < 11; pw++) {
          int ki = pw - qw; if (ki < 0) ki += 11;  // compile-time
          accv[pw] = fmaf(R[qw], K[ki], accv[pw]);
        }
      }
    }
#pragma unroll
    for (int pw = 0; pw < 11; pw++)
      lo[(ph * 11 + pw) * FC + pl] = f2bf(accv[pw]);
  }
  __syncthreads();

  const unsigned int* lou = (const unsigned int*)lo;
#pragma unroll
  for (int i = 0; i < 6; i++) {
    int idx = tid + i * 384;
    if (idx < 1936) {
      int p = idx >> 4;
      int j = idx & 15;
      ((unsigned int*)(xf + (size_t)(b * HW + p) * C_DIM + c0))[j] = lou[idx];
    }
  }
}

// ---------------------------------------------------------------------------
// Pass 3: GEMM D[o][n] = sum_c Wb[o][c] * xf[n][c]
// 256x256 tile, BK=64, 512 thr (8 waves 2Mx4N, each 128x64 out),
// 8-phase schedule, vmcnt(0) drains at ph4/ph8, LDS XOR-swizzle, setprio.
//
// LDS (128 KiB): buf b at byte b*65536:
//   A: [0,32768)  rows quarter-reordered [Q0|Q2|Q1|Q3] (Qk = logical m-rows
//      k*64..k*64+63), 128 B/row (64 bf16). AE half = first 16KB (Q0,Q2 =
//      MH0 for both wave-rows, last ds_read ph1/5), AL = second 16KB (MH1,
//      last read ph3/7).
//   B: [32768,65536) rows 0..255 = n-rows n0..n0+255 linear, last read ph2/6.
// Swizzle: LDS(row, seg16B) holds global seg (seg ^ (row&7)); staged by
// pre-XORing the per-thread GLOBAL column (LDS dest stays linear), ds_read
// applies the same XOR. Breaks the 16-way stride-128B conflict.
//
// Per-iter (tiles T=2it in buf0 ph1-4, T+1 in buf1 ph5-8); issues:
//   ph1: AL(T+1)->b1   ph2: AE(T+2)->b0   ph3: B0(T+2)->b0
//   ph4: VM0, then B1(T+2)->b0           (drain BEFORE issue)
//   ph5: AL(T+2)->b0   ph6: AE(T+3)->b1   ph7: B0(T+3)->b1
//   ph8: VM0, then B1(T+3)->b1
// WAR: every issue is >=1 phase after the target region's last ds_read.
// RAW: ph4's VM0 lands {AL(T+1), B1(T+1), AE(T+2), B0(T+2)} before ph5-7
//      read T+1; ph8's VM0 lands {AL(T+2), AE(T+3), B0(T+3)} before next
//      ph1-3 read T+2; B1 always lands at the NEXT drain, one half-iter
//      before first read. vmcnt(0) is count-independent (spill-safe).
// All global_load_lds use offset=0; K-advance lives in the pointers.
// ---------------------------------------------------------------------------

#define SCHED __builtin_amdgcn_sched_barrier(0)
#define BAR do { SCHED; __builtin_amdgcn_s_barrier(); SCHED; } while (0)
#define LGKM0 do { asm volatile("s_waitcnt lgkmcnt(0)" ::: "memory"); SCHED; } while (0)
#define VM0 asm volatile("s_waitcnt vmcnt(0)" ::: "memory")
#define P1 __builtin_amdgcn_s_setprio(1)
#define P0 __builtin_amdgcn_s_setprio(0)

#define RDA(BUF, MH) do { \
  const char* _pa = pa0 + (BUF)*65536 + (MH)*16384; \
  _Pragma("unroll") \
  for (int _i = 0; _i < 4; ++_i) { \
    a[_i][0] = *(const bfrag*)(_pa + _i*2048 + sx0); \
    a[_i][1] = *(const bfrag*)(_pa + _i*2048 + sx1); \
  } } while (0)

#define RDB(BUF, NH) do { \
  const char* _pb = pb0 + (BUF)*65536 + (NH)*4096; \
  _Pragma("unroll") \
  for (int _j = 0; _j < 2; ++_j) { \
    b[(NH)*2+_j][0] = *(const bfrag*)(_pb + _j*2048 + sx0); \
    b[(NH)*2+_j][1] = *(const bfrag*)(_pb + _j*2048 + sx1); \
  } } while (0)

#define MM(MH, NH) do { \
  _Pragma("unroll") \
  for (int _i = 0; _i < 4; ++_i) { \
    _Pragma("unroll") \
    for (int _j = 0; _j < 2; ++_j) { \
      f32x4 _c = acc[(MH)*4+_i][(NH)*2+_j]; \
      _c = __builtin_amdgcn_mfma_f32_16x16x32_bf16(a[_i][0], b[(NH)*2+_j][0], _c, 0, 0, 0); \
      _c = __builtin_amdgcn_mfma_f32_16x16x32_bf16(a[_i][1], b[(NH)*2+_j][1], _c, 0, 0, 0); \
      acc[(MH)*4+_i][(NH)*2+_j] = _c; \
    } } } while (0)

__global__ __launch_bounds__(512, 2) void gemm256_kernel(
    const unsigned short* __restrict__ Wb, const unsigned short* __restrict__ xf,
    const float* __restrict__ xres, const float* __restrict__ alpha,
    const float* __restrict__ beta2, const float* __restrict__ gate,
    float* __restrict__ out) {
  __shared__ __align__(16) unsigned short lds[65536];  // 128 KiB
  const int tid = threadIdx.x;
  const int lane = tid & 63;
  const int wid = tid >> 6;
  const int fr = lane & 15;
  const int quad = lane >> 4;
  const int wrow = wid >> 2;   // 0..1 (M)
  const int wcol = wid & 3;    // 0..3 (N)

  // XCD-bijective swizzle (488 = 8*61), m-fast so 8 blocks share a B panel.
  const int bid = blockIdx.x;
  const int wg = (bid & 7) * 61 + (bid >> 3);
  const int m0 = (wg & 7) << 8;
  const int n0 = (wg >> 3) << 8;

  // ---- staging pointers (global), pre-swizzled column ----
  const int rowoff = tid >> 3;                              // 0..63
  const int sg8 = ((tid & 7) ^ ((tid >> 3) & 7)) << 3;      // shorts
  const unsigned short* pA00 = Wb + (size_t)(m0 + rowoff) * C_DIM + sg8;        // AE r0 (Q0)
  const unsigned short* pA01 = Wb + (size_t)(m0 + 128 + rowoff) * C_DIM + sg8;  // AE r1 (Q2)
  const unsigned short* pA10 = Wb + (size_t)(m0 + 64 + rowoff) * C_DIM + sg8;   // AL r0 (Q1)
  const unsigned short* pA11 = Wb + (size_t)(m0 + 192 + rowoff) * C_DIM + sg8;  // AL r1 (Q3)
  int nr0 = n0 + rowoff;        if (nr0 > NTOT - 1) nr0 = NTOT - 1;
  int nr1 = n0 + 64 + rowoff;   if (nr1 > NTOT - 1) nr1 = NTOT - 1;
  int nr2 = n0 + 128 + rowoff;  if (nr2 > NTOT - 1) nr2 = NTOT - 1;
  int nr3 = n0 + 192 + rowoff;  if (nr3 > NTOT - 1) nr3 = NTOT - 1;
  const unsigned short* pB00 = xf + (size_t)nr0 * C_DIM + sg8;  // B0 r0
  const unsigned short* pB01 = xf + (size_t)nr1 * C_DIM + sg8;  // B0 r1
  const unsigned short* pB10 = xf + (size_t)nr2 * C_DIM + sg8;  // B1 r0
  const unsigned short* pB11 = xf + (size_t)nr3 * C_DIM + sg8;  // B1 r1

  char* Lc = (char*)lds;
  char* Ld = Lc + tid * 16;  // linear gload_lds dest (wave-uniform base + lane*16)

  // ---- fragment read bases (swizzled) ----
  const int fx = fr & 7;
  const int sx0 = ((quad ^ fx) << 4);        // ks=0: global kseg = quad
  const int sx1 = (((4 + quad) ^ fx) << 4);  // ks=1: global kseg = 4+quad
  const char* pa0 = Lc + (wrow << 13) + (fr << 7);          // + MH*16384 + i*2048
  const char* pb0 = Lc + 32768 + (wcol << 13) + (fr << 7);  // + NH*4096 + j*2048

  f32x4 acc[8][4];
#pragma unroll
  for (int i = 0; i < 8; ++i)
#pragma unroll
    for (int j = 0; j < 4; ++j) acc[i][j] = f32x4{0.f, 0.f, 0.f, 0.f};
  bfrag a[4][2], b[4][2];

  // OFFB is a BYTE offset applied to the GLOBAL pointer (builtin offset = 0).
#define G16(P, OFFB, LOFF) \
  gload16((const unsigned short*)((const char*)(P) + (OFFB)), Ld + (LOFF))
#define ISS1 do { G16(pA10, 128, 65536+16384); G16(pA11, 128, 65536+16384+8192); } while (0)
#define ISS2 do { G16(pA00, 256, 0);           G16(pA01, 256, 8192); } while (0)
#define ISS3 do { G16(pB00, 256, 32768);       G16(pB01, 256, 32768+8192); } while (0)
#define ISS4 do { G16(pB10, 256, 32768+16384); G16(pB11, 256, 32768+16384+8192); } while (0)
#define ISS5 do { G16(pA10, 256, 16384);       G16(pA11, 256, 16384+8192); } while (0)
#define ISS6 do { G16(pA00, 384, 65536);       G16(pA01, 384, 65536+8192); } while (0)
#define ISS7 do { G16(pB00, 384, 65536+32768); G16(pB01, 384, 65536+32768+8192); } while (0)
#define ISS8 do { G16(pB10, 384, 65536+32768+16384); G16(pB11, 384, 65536+32768+16384+8192); } while (0)

  // ---- prologue ----
  // tile0: all 4 regions -> buf0
  G16(pA00, 0, 0);               G16(pA01, 0, 8192);
  G16(pA10, 0, 16384);           G16(pA11, 0, 16384+8192);
  G16(pB00, 0, 32768);           G16(pB01, 0, 32768+8192);
  G16(pB10, 0, 32768+16384);     G16(pB11, 0, 32768+16384+8192);
  SCHED;
  VM0;  // full drain: tile0 landed regardless of issue order
  SCHED;
  // tile1: AE,B0,B1 -> buf1
  G16(pA00, 128, 65536);         G16(pA01, 128, 65536+8192);
  G16(pB00, 128, 65536+32768);   G16(pB01, 128, 65536+32768+8192);
  G16(pB10, 128, 65536+32768+16384); G16(pB11, 128, 65536+32768+16384+8192);
  SCHED;
  BAR;  // all waves' tile0 visible

#pragma unroll 1
  for (int it = 0; it < 16; ++it) {
    const bool full = (it < 15);
    // ph1 (buf0, mh0, nh0)
    RDA(0, 0); RDB(0, 0);
    ISS1;
    BAR; LGKM0; P1; MM(0, 0); P0; BAR;
    // ph2 (buf0, mh0, nh1)
    RDB(0, 1);
    if (full) ISS2;
    BAR; LGKM0; P1; MM(0, 1); P0; BAR;
    // ph3 (buf0, mh1, nh0)
    RDA(0, 1);
    if (full) ISS3;
    BAR; LGKM0; P1; MM(1, 0); P0; BAR;
    // ph4 (buf0, mh1, nh1): drain, THEN issue B1(T+2)
    SCHED; VM0; SCHED;
    if (full) ISS4;
    BAR; LGKM0; P1; MM(1, 1); P0; BAR;
    // ph5 (buf1, mh0, nh0)
    RDA(1, 0); RDB(1, 0);
    if (full) ISS5;
    BAR; LGKM0; P1; MM(0, 0); P0; BAR;
    // ph6 (buf1, mh0, nh1)
    RDB(1, 1);
    if (full) ISS6;
    BAR; LGKM0; P1; MM(0, 1); P0; BAR;
    // ph7 (buf1, mh1, nh0)
    RDA(1, 1);
    if (full) ISS7;
    BAR; LGKM0; P1; MM(1, 0); P0; BAR;
    // ph8 (buf1, mh1, nh1): drain, THEN issue B1(T+3)
    SCHED; VM0; SCHED;
    if (full) ISS8;
    BAR; LGKM0; P1; MM(1, 1); P0; BAR;
    // advance K by 2 tiles (128 shorts)
    pA00 += 128; pA01 += 128; pA10 += 128; pA11 += 128;
    pB00 += 128; pB01 += 128; pB10 += 128; pB11 += 128;
  }

  // ---- epilogue: BN + ReLU + gated residual ----
  float g = gate[0];
  g = fminf(fmaxf(g, 0.0f), 1.0f);
  int nb[4];
  bool nv[4];
#pragma unroll
  for (int nh = 0; nh < 2; ++nh)
#pragma unroll
    for (int j = 0; j < 2; ++j) {
      const int idx = nh * 2 + j;
      int n = n0 + wcol * 64 + nh * 32 + j * 16 + fr;
      nv[idx] = (n < NTOT);
      int bb = n / 121;
      int p = n - bb * 121;
      if (!nv[idx]) { bb = 0; p = 0; }
      nb[idx] = bb * (C_DIM * HW) + p;
    }
#pragma unroll
  for (int mh = 0; mh < 2; ++mh)
#pragma unroll
    for (int i2 = 0; i2 < 4; ++i2) {
      const int ob = m0 + wrow * 128 + mh * 64 + i2 * 16 + quad * 4;
      const float4 al = *(const float4*)(alpha + ob);
      const float4 bt = *(const float4*)(beta2 + ob);
#pragma unroll
      for (int idx = 0; idx < 4; ++idx) {
        if (nv[idx]) {
#pragma unroll
          for (int rr = 0; rr < 4; ++rr) {
            int addr = nb[idx] + (ob + rr) * HW;
            float v = acc[mh * 4 + i2][idx][rr] * (&al.x)[rr] + (&bt.x)[rr];
            v = fmaxf(v, 0.0f);
            out[addr] = xres[addr] + g * v;
          }
        }
      }
    }
}

// ---------------------------------------------------------------------------
// Workspace layout (~76 MB):
//   [0x000000, +1441792)  kws: 2048 x 176 fp32 spatial kernels (row pad 16)
//   [0x200000, +8192)     alpha
//   [0x202000, +8192)     beta2
//   [0x300000, +8388608)  Wb bf16 [2048][2048]
//   [0xC00000, +63438848) xf bf16 [15488][2048]
// ---------------------------------------------------------------------------
extern "C" void kernel_launch(void* const* d_in, const int* in_sizes, int n_in,
                              void* d_out, int out_size, void* d_ws, size_t ws_size,
                              hipStream_t stream) {
  const float* x     = (const float*)d_in[0];
  const float* ft    = (const float*)d_in[1];
  const float* gate  = (const float*)d_in[2];
  const float* W     = (const float*)d_in[3];
  const float* convb = (const float*)d_in[4];
  const float* gamma = (const float*)d_in[5];
  const float* beta  = (const float*)d_in[6];
  const float* mean  = (const float*)d_in[7];
  const float* var   = (const float*)d_in[8];
  float* out = (float*)d_out;

  char* ws = (char*)d_ws;
  float* kws            = (float*)(ws);
  float* alpha          = (float*)(ws + 0x200000);
  float* beta2          = (float*)(ws + 0x202000);
  unsigned short* Wb    = (unsigned short*)(ws + 0x300000);
  unsigned short* xf    = (unsigned short*)(ws + 0xC00000);

  prep_kernel<<<2048, 256, 0, stream>>>(ft, convb, gamma, beta, mean, var,
                                        W, Wb, kws, alpha, beta2);
  filter_kernel<<<dim3(NB, C_DIM / FC), 384, 0, stream>>>(x, kws, xf);
  gemm256_kernel<<<dim3(488), 512, 0, stream>>>(Wb, xf, x, alpha, beta2, gate, out);
}

// Round 5
// 456.758 us; speedup vs baseline: 1.0342x; 1.0060x over previous
//
#include <hip/hip_runtime.h>
#include <cstdint>
#include <cstddef>

// ---------------------------------------------------------------------------
// FFTFrequencyFilter: FFT highpass (== circular conv with per-channel 11x11
// kernel) -> 1x1 conv (GEMM, bf16 MFMA) -> BN -> ReLU -> gated residual.
// B=128, C=2048, H=W=11 (HW=121), N = B*HW = 15488.
// R9: R8 (passing) with counted vmcnt(6) restored at ph4/ph8 (ISS then
//     count), vmcnt(0) only in the tail iteration. R8's counters proved
//     VGPR=128 / no scratch -> the vmcnt event stream contains only the 16
//     staging loads per iter, so the count is exact. All offsets remain in
//     the GLOBAL POINTER (global_load_lds offset arg always 0 — the R5-R7
//     corruption source). prep/filter identical to R4.
// ---------------------------------------------------------------------------

#define C_DIM 2048
#define HW 121
#define NB 128
#define NTOT (NB * HW)  // 15488

__device__ __forceinline__ unsigned short f2bf(float f) {
  union { float f; unsigned int u; } v;
  v.f = f;
  unsigned int r = (v.u + 0x7FFFu + ((v.u >> 16) & 1u)) >> 16;
  return (unsigned short)r;
}

typedef __bf16 bfrag __attribute__((ext_vector_type(8)));
typedef float f32x4 __attribute__((ext_vector_type(4)));

__device__ __forceinline__ void gload16(const unsigned short* g, char* l) {
  __builtin_amdgcn_global_load_lds(
      (const __attribute__((address_space(1))) unsigned int*)(uintptr_t)g,
      (__attribute__((address_space(3))) unsigned int*)(uintptr_t)l, 16, 0, 0);
}

// ---------------------------------------------------------------------------
// Pass 1: per-channel spatial kernel k_c[11][11] (row-padded to 16 floats),
// epilogue constants alpha/beta2, AND W fp32->bf16 (row c per block).
// (unchanged from R4)
// ---------------------------------------------------------------------------
__global__ __launch_bounds__(256) void prep_kernel(
    const float* __restrict__ ft, const float* __restrict__ convb,
    const float* __restrict__ gamma, const float* __restrict__ beta,
    const float* __restrict__ mean, const float* __restrict__ var,
    const float* __restrict__ W, unsigned short* __restrict__ Wb,
    float* __restrict__ kws, float* __restrict__ alpha,
    float* __restrict__ beta2) {
  __shared__ float msk[121];
  __shared__ float ctab[11];
  const int c = blockIdx.x;
  const int t = threadIdx.x;

  {
    int base = c * C_DIM + t * 8;
    float4 a = *(const float4*)(W + base);
    float4 b = *(const float4*)(W + base + 4);
    union { unsigned short s[8]; uint4 v; } u;
    u.s[0] = f2bf(a.x); u.s[1] = f2bf(a.y); u.s[2] = f2bf(a.z); u.s[3] = f2bf(a.w);
    u.s[4] = f2bf(b.x); u.s[5] = f2bf(b.y); u.s[6] = f2bf(b.z); u.s[7] = f2bf(b.w);
    *(uint4*)(Wb + base) = u.v;
  }

  float cutoff = ft[c];
  cutoff = fminf(fmaxf(cutoff, 0.05f), 0.5f);
  if (t < 121) {
    int h = t / 11, w = t - (t / 11) * 11;
    float dy = (float)(h - 5), dx = (float)(w - 5);
    float dn = sqrtf(dy * dy + dx * dx) / (sqrtf(50.0f) + 1e-6f);
    msk[t] = 1.0f / (1.0f + expf(-10.0f * (dn - cutoff)));
  }
  if (t < 11) ctab[t] = cosf(6.283185307179586f * (float)t / 11.0f);
  if (t == 128) {
    float inv = gamma[c] * rsqrtf(var[c] + 1e-5f);
    alpha[c] = inv;
    beta2[c] = (convb[c] - mean[c]) * inv + beta[c];
  }
  __syncthreads();
  if (t < 176) {  // 11 rows x 16 padded cols
    int h = t >> 4, w = t & 15;
    float val = 0.0f;
    if (w < 11) {
      float acc = 0.0f;
      int ru = 0;
      int us = 5;
      for (int u = 0; u < 11; u++) {
        int rv = ru;
        int vs = 5;
        for (int v = 0; v < 11; v++) {
          acc += msk[us * 11 + vs] * ctab[rv];
          rv += w; if (rv >= 11) rv -= 11;
          vs++; if (vs >= 11) vs -= 11;
        }
        ru += h; if (ru >= 11) ru -= 11;
        us++; if (us >= 11) us -= 11;
      }
      val = acc * (1.0f / 121.0f);
    }
    kws[(size_t)c * 176 + t] = val;
  }
}

// ---------------------------------------------------------------------------
// Pass 2: circular conv filter using k's h-symmetry. (unchanged from R4)
// ---------------------------------------------------------------------------
#define XROW 12
#define XPL 132
#define FC 32
__global__ __launch_bounds__(384) void filter_kernel(
    const float* __restrict__ x, const float* __restrict__ kws,
    unsigned short* __restrict__ xf) {
  __shared__ __align__(16) float lx[FC * XPL];          // 16896 B
  __shared__ __align__(16) unsigned short lo[HW * FC];  // 7744 B
  const int b = blockIdx.x;
  const int c0 = blockIdx.y * FC;
  const int tid = threadIdx.x;

  const float* xsrc = x + ((size_t)b * C_DIM + c0) * HW;
#pragma unroll
  for (int i = 0; i < 3; i++) {
    int v = tid + i * 384;
    if (v < 968) {
      float4 xv = *(const float4*)(xsrc + v * 4);
      int g = v * 4;
#pragma unroll
      for (int e = 0; e < 4; e++) {
        int ge = g + e;
        int pl = ge / 121;
        int r = ge - pl * 121;
        int rh = r / 11;
        int rw = r - rh * 11;
        lx[pl * XPL + rh * XROW + rw] = (&xv.x)[e];
      }
    }
  }
  __syncthreads();

  if (tid < 352) {
    const int pl = tid / 11;
    const int ph = tid - pl * 11;
    const float* xp = &lx[pl * XPL];
    const float* kp = kws + (size_t)(c0 + pl) * 176;

    float accv[11];
#pragma unroll
    for (int i = 0; i < 11; i++) accv[i] = 0.f;

#pragma unroll
    for (int d = 0; d <= 5; d++) {
      int q0 = ph - d; if (q0 < 0) q0 += 11;
      f32x4 r0 = *(const f32x4*)(xp + q0 * XROW);
      f32x4 r1 = *(const f32x4*)(xp + q0 * XROW + 4);
      f32x4 r2 = *(const f32x4*)(xp + q0 * XROW + 8);
      if (d > 0) {
        int q1 = ph + d; if (q1 >= 11) q1 -= 11;
        r0 += *(const f32x4*)(xp + q1 * XROW);
        r1 += *(const f32x4*)(xp + q1 * XROW + 4);
        r2 += *(const f32x4*)(xp + q1 * XROW + 8);
      }
      const float R[11] = {r0[0], r0[1], r0[2], r0[3], r1[0], r1[1],
                           r1[2], r1[3], r2[0], r2[1], r2[2]};
      f32x4 k0 = *(const f32x4*)(kp + d * 16);
      f32x4 k1 = *(const f32x4*)(kp + d * 16 + 4);
      f32x4 k2 = *(const f32x4*)(kp + d * 16 + 8);
      const float K[11] = {k0[0], k0[1], k0[2], k0[3], k1[0], k1[1],
                           k1[2], k1[3], k2[0], k2[1], k2[2]};
#pragma unroll
      for (int qw = 0; qw < 11; qw++) {
#pragma unroll
        for (int pw = 0; pw < 11; pw++) {
          int ki = pw - qw; if (ki < 0) ki += 11;  // compile-time
          accv[pw] = fmaf(R[qw], K[ki], accv[pw]);
        }
      }
    }
#pragma unroll
    for (int pw = 0; pw < 11; pw++)
      lo[(ph * 11 + pw) * FC + pl] = f2bf(accv[pw]);
  }
  __syncthreads();

  const unsigned int* lou = (const unsigned int*)lo;
#pragma unroll
  for (int i = 0; i < 6; i++) {
    int idx = tid + i * 384;
    if (idx < 1936) {
      int p = idx >> 4;
      int j = idx & 15;
      ((unsigned int*)(xf + (size_t)(b * HW + p) * C_DIM + c0))[j] = lou[idx];
    }
  }
}

// ---------------------------------------------------------------------------
// Pass 3: GEMM D[o][n] = sum_c Wb[o][c] * xf[n][c]
// 256x256 tile, BK=64, 512 thr (8 waves 2Mx4N, each 128x64 out),
// 8-phase schedule, counted vmcnt(6) at ph4/ph8, LDS XOR-swizzle, setprio.
//
// LDS (128 KiB): buf b at byte b*65536:
//   A: [0,32768)  rows quarter-reordered [Q0|Q2|Q1|Q3] (Qk = logical m-rows
//      k*64..k*64+63), 128 B/row. AE half = first 16KB (MH0, last ds_read
//      ph1/5), AL = second 16KB (MH1, last read ph3/7).
//   B: [32768,65536) rows 0..255 = n-rows n0..n0+255 linear; every B row's
//      last read is ph2/6 (all 4 wave-cols read both NH halves by ph2).
// Swizzle: LDS(row, seg16B) holds global seg (seg ^ (row&7)); staged by
// pre-XORing the per-thread GLOBAL column (LDS dest stays linear), ds_read
// applies the same XOR. Bank-conflict-free (R8 PMC: 0).
//
// Per-iter (tiles T=2it in buf0 ph1-4, T+1 in buf1 ph5-8); issues (2 loads
// each): ph1 AL(T+1)->b1, ph2 AE(T+2)->b0, ph3 B0(T+2)->b0,
//        ph4 B1(T+2)->b0 then vmcnt(6),
//        ph5 AL(T+2)->b0, ph6 AE(T+3)->b1, ph7 B0(T+3)->b1,
//        ph8 B1(T+3)->b1 then vmcnt(6).
// Ledger (loads): entering ph1 = 6 {AE,B0,B1 of T+1}; +2/phase -> 14 at
// ph4; vmcnt(6) retires oldest 8 = ALL of tile T+1 before ph5-8 read it,
// leaving 6 = tile T+2's AE/B0/B1 (invariant restored). Loads land 4+
// phases after issue -> latency hidden. WAR: every issue >=1 phase after
// its region's last read. Tail it=15: only ph1's AL(31) issued; ph4 uses
// vmcnt(0) (8 outstanding, ph5-7 need all of tile31); ph8 vacuous drain.
// Counted vmcnt is exact: in-loop VMEM = staging loads only (R8: VGPR=128,
// no scratch). All global_load_lds use offset=0; K-advance in pointers.
// ---------------------------------------------------------------------------

#define SCHED __builtin_amdgcn_sched_barrier(0)
#define BAR do { SCHED; __builtin_amdgcn_s_barrier(); SCHED; } while (0)
#define LGKM0 do { asm volatile("s_waitcnt lgkmcnt(0)" ::: "memory"); SCHED; } while (0)
#define VM6 asm volatile("s_waitcnt vmcnt(6)" ::: "memory")
#define VM0 asm volatile("s_waitcnt vmcnt(0)" ::: "memory")
#define P1 __builtin_amdgcn_s_setprio(1)
#define P0 __builtin_amdgcn_s_setprio(0)

#define RDA(BUF, MH) do { \
  const char* _pa = pa0 + (BUF)*65536 + (MH)*16384; \
  _Pragma("unroll") \
  for (int _i = 0; _i < 4; ++_i) { \
    a[_i][0] = *(const bfrag*)(_pa + _i*2048 + sx0); \
    a[_i][1] = *(const bfrag*)(_pa + _i*2048 + sx1); \
  } } while (0)

#define RDB(BUF, NH) do { \
  const char* _pb = pb0 + (BUF)*65536 + (NH)*4096; \
  _Pragma("unroll") \
  for (int _j = 0; _j < 2; ++_j) { \
    b[(NH)*2+_j][0] = *(const bfrag*)(_pb + _j*2048 + sx0); \
    b[(NH)*2+_j][1] = *(const bfrag*)(_pb + _j*2048 + sx1); \
  } } while (0)

#define MM(MH, NH) do { \
  _Pragma("unroll") \
  for (int _i = 0; _i < 4; ++_i) { \
    _Pragma("unroll") \
    for (int _j = 0; _j < 2; ++_j) { \
      f32x4 _c = acc[(MH)*4+_i][(NH)*2+_j]; \
      _c = __builtin_amdgcn_mfma_f32_16x16x32_bf16(a[_i][0], b[(NH)*2+_j][0], _c, 0, 0, 0); \
      _c = __builtin_amdgcn_mfma_f32_16x16x32_bf16(a[_i][1], b[(NH)*2+_j][1], _c, 0, 0, 0); \
      acc[(MH)*4+_i][(NH)*2+_j] = _c; \
    } } } while (0)

__global__ __launch_bounds__(512, 2) void gemm256_kernel(
    const unsigned short* __restrict__ Wb, const unsigned short* __restrict__ xf,
    const float* __restrict__ xres, const float* __restrict__ alpha,
    const float* __restrict__ beta2, const float* __restrict__ gate,
    float* __restrict__ out) {
  __shared__ __align__(16) unsigned short lds[65536];  // 128 KiB
  const int tid = threadIdx.x;
  const int lane = tid & 63;
  const int wid = tid >> 6;
  const int fr = lane & 15;
  const int quad = lane >> 4;
  const int wrow = wid >> 2;   // 0..1 (M)
  const int wcol = wid & 3;    // 0..3 (N)

  // XCD-bijective swizzle (488 = 8*61), m-fast so 8 blocks share a B panel.
  const int bid = blockIdx.x;
  const int wg = (bid & 7) * 61 + (bid >> 3);
  const int m0 = (wg & 7) << 8;
  const int n0 = (wg >> 3) << 8;

  // ---- staging pointers (global), pre-swizzled column ----
  const int rowoff = tid >> 3;                              // 0..63
  const int sg8 = ((tid & 7) ^ ((tid >> 3) & 7)) << 3;      // shorts
  const unsigned short* pA00 = Wb + (size_t)(m0 + rowoff) * C_DIM + sg8;        // AE r0 (Q0)
  const unsigned short* pA01 = Wb + (size_t)(m0 + 128 + rowoff) * C_DIM + sg8;  // AE r1 (Q2)
  const unsigned short* pA10 = Wb + (size_t)(m0 + 64 + rowoff) * C_DIM + sg8;   // AL r0 (Q1)
  const unsigned short* pA11 = Wb + (size_t)(m0 + 192 + rowoff) * C_DIM + sg8;  // AL r1 (Q3)
  int nr0 = n0 + rowoff;        if (nr0 > NTOT - 1) nr0 = NTOT - 1;
  int nr1 = n0 + 64 + rowoff;   if (nr1 > NTOT - 1) nr1 = NTOT - 1;
  int nr2 = n0 + 128 + rowoff;  if (nr2 > NTOT - 1) nr2 = NTOT - 1;
  int nr3 = n0 + 192 + rowoff;  if (nr3 > NTOT - 1) nr3 = NTOT - 1;
  const unsigned short* pB00 = xf + (size_t)nr0 * C_DIM + sg8;  // B0 r0
  const unsigned short* pB01 = xf + (size_t)nr1 * C_DIM + sg8;  // B0 r1
  const unsigned short* pB10 = xf + (size_t)nr2 * C_DIM + sg8;  // B1 r0
  const unsigned short* pB11 = xf + (size_t)nr3 * C_DIM + sg8;  // B1 r1

  char* Lc = (char*)lds;
  char* Ld = Lc + tid * 16;  // linear gload_lds dest (wave-uniform base + lane*16)

  // ---- fragment read bases (swizzled) ----
  const int fx = fr & 7;
  const int sx0 = ((quad ^ fx) << 4);        // ks=0: global kseg = quad
  const int sx1 = (((4 + quad) ^ fx) << 4);  // ks=1: global kseg = 4+quad
  const char* pa0 = Lc + (wrow << 13) + (fr << 7);          // + MH*16384 + i*2048
  const char* pb0 = Lc + 32768 + (wcol << 13) + (fr << 7);  // + NH*4096 + j*2048

  f32x4 acc[8][4];
#pragma unroll
  for (int i = 0; i < 8; ++i)
#pragma unroll
    for (int j = 0; j < 4; ++j) acc[i][j] = f32x4{0.f, 0.f, 0.f, 0.f};
  bfrag a[4][2], b[4][2];

  // OFFB is a BYTE offset applied to the GLOBAL pointer (builtin offset = 0).
#define G16(P, OFFB, LOFF) \
  gload16((const unsigned short*)((const char*)(P) + (OFFB)), Ld + (LOFF))
#define ISS1 do { G16(pA10, 128, 65536+16384); G16(pA11, 128, 65536+16384+8192); } while (0)
#define ISS2 do { G16(pA00, 256, 0);           G16(pA01, 256, 8192); } while (0)
#define ISS3 do { G16(pB00, 256, 32768);       G16(pB01, 256, 32768+8192); } while (0)
#define ISS4 do { G16(pB10, 256, 32768+16384); G16(pB11, 256, 32768+16384+8192); } while (0)
#define ISS5 do { G16(pA10, 256, 16384);       G16(pA11, 256, 16384+8192); } while (0)
#define ISS6 do { G16(pA00, 384, 65536);       G16(pA01, 384, 65536+8192); } while (0)
#define ISS7 do { G16(pB00, 384, 65536+32768); G16(pB01, 384, 65536+32768+8192); } while (0)
#define ISS8 do { G16(pB10, 384, 65536+32768+16384); G16(pB11, 384, 65536+32768+16384+8192); } while (0)

  // ---- prologue ----
  // tile0: all 4 regions -> buf0
  G16(pA00, 0, 0);               G16(pA01, 0, 8192);
  G16(pA10, 0, 16384);           G16(pA11, 0, 16384+8192);
  G16(pB00, 0, 32768);           G16(pB01, 0, 32768+8192);
  G16(pB10, 0, 32768+16384);     G16(pB11, 0, 32768+16384+8192);
  SCHED;
  VM0;  // full drain: tile0 landed regardless of issue order
  SCHED;
  // tile1: AE,B0,B1 -> buf1 (6 outstanding = steady-state invariant)
  G16(pA00, 128, 65536);         G16(pA01, 128, 65536+8192);
  G16(pB00, 128, 65536+32768);   G16(pB01, 128, 65536+32768+8192);
  G16(pB10, 128, 65536+32768+16384); G16(pB11, 128, 65536+32768+16384+8192);
  SCHED;
  BAR;  // all waves' tile0 visible

#pragma unroll 1
  for (int it = 0; it < 16; ++it) {
    const bool full = (it < 15);
    // ph1 (buf0, mh0, nh0)
    RDA(0, 0); RDB(0, 0);
    ISS1;
    BAR; LGKM0; P1; MM(0, 0); P0; BAR;
    // ph2 (buf0, mh0, nh1)
    RDB(0, 1);
    if (full) ISS2;
    BAR; LGKM0; P1; MM(0, 1); P0; BAR;
    // ph3 (buf0, mh1, nh0)
    RDA(0, 1);
    if (full) ISS3;
    BAR; LGKM0; P1; MM(1, 0); P0; BAR;
    // ph4 (buf0, mh1, nh1): issue B1(T+2), then counted wait
    if (full) { ISS4; SCHED; VM6; } else { SCHED; VM0; }
    BAR; LGKM0; P1; MM(1, 1); P0; BAR;
    // ph5 (buf1, mh0, nh0)
    RDA(1, 0); RDB(1, 0);
    if (full) ISS5;
    BAR; LGKM0; P1; MM(0, 0); P0; BAR;
    // ph6 (buf1, mh0, nh1)
    RDB(1, 1);
    if (full) ISS6;
    BAR; LGKM0; P1; MM(0, 1); P0; BAR;
    // ph7 (buf1, mh1, nh0)
    RDA(1, 1);
    if (full) ISS7;
    BAR; LGKM0; P1; MM(1, 0); P0; BAR;
    // ph8 (buf1, mh1, nh1): issue B1(T+3), then counted wait
    if (full) { ISS8; SCHED; VM6; } else { SCHED; VM0; }
    BAR; LGKM0; P1; MM(1, 1); P0; BAR;
    // advance K by 2 tiles (128 shorts)
    pA00 += 128; pA01 += 128; pA10 += 128; pA11 += 128;
    pB00 += 128; pB01 += 128; pB10 += 128; pB11 += 128;
  }

  // ---- epilogue: BN + ReLU + gated residual ----
  float g = gate[0];
  g = fminf(fmaxf(g, 0.0f), 1.0f);
  int nb[4];
  bool nv[4];
#pragma unroll
  for (int nh = 0; nh < 2; ++nh)
#pragma unroll
    for (int j = 0; j < 2; ++j) {
      const int idx = nh * 2 + j;
      int n = n0 + wcol * 64 + nh * 32 + j * 16 + fr;
      nv[idx] = (n < NTOT);
      int bb = n / 121;
      int p = n - bb * 121;
      if (!nv[idx]) { bb = 0; p = 0; }
      nb[idx] = bb * (C_DIM * HW) + p;
    }
#pragma unroll
  for (int mh = 0; mh < 2; ++mh)
#pragma unroll
    for (int i2 = 0; i2 < 4; ++i2) {
      const int ob = m0 + wrow * 128 + mh * 64 + i2 * 16 + quad * 4;
      const float4 al = *(const float4*)(alpha + ob);
      const float4 bt = *(const float4*)(beta2 + ob);
#pragma unroll
      for (int idx = 0; idx < 4; ++idx) {
        if (nv[idx]) {
#pragma unroll
          for (int rr = 0; rr < 4; ++rr) {
            int addr = nb[idx] + (ob + rr) * HW;
            float v = acc[mh * 4 + i2][idx][rr] * (&al.x)[rr] + (&bt.x)[rr];
            v = fmaxf(v, 0.0f);
            out[addr] = xres[addr] + g * v;
          }
        }
      }
    }
}

// ---------------------------------------------------------------------------
// Workspace layout (~76 MB):
//   [0x000000, +1441792)  kws: 2048 x 176 fp32 spatial kernels (row pad 16)
//   [0x200000, +8192)     alpha
//   [0x202000, +8192)     beta2
//   [0x300000, +8388608)  Wb bf16 [2048][2048]
//   [0xC00000, +63438848) xf bf16 [15488][2048]
// ---------------------------------------------------------------------------
extern "C" void kernel_launch(void* const* d_in, const int* in_sizes, int n_in,
                              void* d_out, int out_size, void* d_ws, size_t ws_size,
                              hipStream_t stream) {
  const float* x     = (const float*)d_in[0];
  const float* ft    = (const float*)d_in[1];
  const float* gate  = (const float*)d_in[2];
  const float* W     = (const float*)d_in[3];
  const float* convb = (const float*)d_in[4];
  const float* gamma = (const float*)d_in[5];
  const float* beta  = (const float*)d_in[6];
  const float* mean  = (const float*)d_in[7];
  const float* var   = (const float*)d_in[8];
  float* out = (float*)d_out;

  char* ws = (char*)d_ws;
  float* kws            = (float*)(ws);
  float* alpha          = (float*)(ws + 0x200000);
  float* beta2          = (float*)(ws + 0x202000);
  unsigned short* Wb    = (unsigned short*)(ws + 0x300000);
  unsigned short* xf    = (unsigned short*)(ws + 0xC00000);

  prep_kernel<<<2048, 256, 0, stream>>>(ft, convb, gamma, beta, mean, var,
                                        W, Wb, kws, alpha, beta2);
  filter_kernel<<<dim3(NB, C_DIM / FC), 384, 0, stream>>>(x, kws, xf);
  gemm256_kernel<<<dim3(488), 512, 0, stream>>>(Wb, xf, x, alpha, beta2, gate, out);
}